// Round 10
// baseline (186.010 us; speedup 1.0000x reference)
//
#include <hip/hip_runtime.h>
#include <hip/hip_bf16.h>

#define HW   56
#define CIN  64
#define OC   512
#define NPIX (HW * HW)   // 3136
#define PEL  ((size_t)8 * NPIX * OC)   // elements per q/k/v tensor

typedef unsigned short ushort_t;
typedef __attribute__((ext_vector_type(8))) short short8;
typedef __attribute__((ext_vector_type(4))) float floatx4;

static __device__ __forceinline__ ushort_t f2bf(float f) {
  __hip_bfloat16 h = __float2bfloat16(f);
  return *(ushort_t*)&h;
}

// ---------------------------------------------------------------------------
// Prepass A: x NCHW fp32 -> xT [b][h][w][c] bf16.  Block per (h, b).
// ---------------------------------------------------------------------------
__global__ __launch_bounds__(256)
void cast_x_kernel(const float* __restrict__ x, ushort_t* __restrict__ xT) {
  __shared__ ushort_t lx[CIN * HW];   // [c][w]
  const int tid = threadIdx.x;
  const int h = blockIdx.x, b = blockIdx.y;
  for (int idx = tid; idx < CIN * HW; idx += 256) {
    int c = idx / HW, w = idx - c * HW;
    lx[idx] = f2bf(x[((size_t)(b * CIN + c) * HW + h) * HW + w]);
  }
  __syncthreads();
  ushort_t* dst = xT + ((size_t)(b * HW + h)) * HW * CIN;
  for (int i = tid; i < (CIN * HW) / 4; i += 256) {
    int e0 = i * 4;
    int w = e0 >> 6, c0 = e0 & 63;
    ushort4 o;
    o.x = lx[(c0 + 0) * HW + w];
    o.y = lx[(c0 + 1) * HW + w];
    o.z = lx[(c0 + 2) * HW + w];
    o.w = lx[(c0 + 3) * HW + w];
    ((ushort4*)dst)[i] = o;
  }
}

// ---------------------------------------------------------------------------
// Prepass B: W [oc][cin][3][3] fp32 -> Wb [tap][j][cin] bf16, 3 tensors
// contiguous.  q,k output row j = c*8+n fed from W row oc = n*64+c (attn
// permutation folded into weights -> identity conv stores).  v = identity.
// ---------------------------------------------------------------------------
__global__ __launch_bounds__(64)
void cast_w_kernel(const float* __restrict__ W0, const float* __restrict__ W1,
                   const float* __restrict__ W2, ushort_t* __restrict__ D) {
  const int cin = threadIdx.x;
  const int j = blockIdx.x, sel = blockIdx.y;
  const float* W = sel == 0 ? W0 : (sel == 1 ? W1 : W2);
  ushort_t* Ds = D + (size_t)sel * 9 * OC * CIN;
  const int src = (sel < 2) ? ((j & 7) * 64 + (j >> 3)) : j;
  #pragma unroll
  for (int tap = 0; tap < 9; ++tap)
    Ds[((size_t)tap * OC + j) * CIN + cin] = f2bf(W[(size_t)src * 576 + cin * 9 + tap]);
}

// ---------------------------------------------------------------------------
// Prepass C: Wu fp32 -> bf16, identity layout (ci = c*8+n already matches a2).
// ---------------------------------------------------------------------------
__global__ __launch_bounds__(512)
void cast_wu_kernel(const float* __restrict__ Wu, ushort_t* __restrict__ WuP) {
  const int co = blockIdx.x, t = threadIdx.x;
  WuP[(size_t)co * 512 + t] = f2bf(Wu[(size_t)co * 512 + t]);
}

// ---------------------------------------------------------------------------
// Kernel 1: q/k/v 3x3 conv, MFMA 16x16x32 bf16 implicit GEMM.
// One tensor pass per block (s = blockIdx.z>>3).  r9 lesson: pipes all <40%
// busy -> latency-bound on the 2-MFMA-per-ds_read inner step.  This round:
// wave owns 64 oc (nt=4) -> 4 MFMA per ds_read_b128, 28 independent MFMAs
// per 7-read group.  VGPR ~220 -> launch_bounds(256,2) (256 cap, no spill).
// ---------------------------------------------------------------------------
#define XLS 72             // padded cin stride in x LDS tile (bf16 units)
#define XROW (58 * XLS)

__global__ __launch_bounds__(256, 2)
void conv3x3_qkv(const ushort_t* __restrict__ xT, const ushort_t* __restrict__ Wb,
                 ushort_t* __restrict__ yq) {
  __shared__ __align__(16) ushort_t xl[4 * XROW];   // 33408 B

  const int tid  = threadIdx.x;
  const int lane = tid & 63;
  const int wv   = tid >> 6;
  const int g    = blockIdx.x;
  const int ob   = blockIdx.y;        // 0,1: which 256-oc half
  const int b    = blockIdx.z & 7;
  const int s    = blockIdx.z >> 3;   // tensor: 0=q 1=k 2=v
  const int h0   = g * 2;
  const int l15  = lane & 15;
  const int quad = lane >> 4;

  int abase[7];
  #pragma unroll
  for (int t = 0; t < 7; ++t) {
    int pix = t * 16 + l15;
    int row = pix / HW, ww = pix - row * HW;
    abase[t] = (row * 58 + ww) * XLS + quad * 8;
  }

  // per-lane B base: tensor s, wave's 64 oc, 8 cin at quad*8
  const ushort_t* wb0 = Wb + (size_t)s * 9 * OC * CIN +
                        ((size_t)(ob * 256 + wv * 64 + l15)) * CIN + quad * 8;

  // ---- stage x rows h0-1 .. h0+2; zero only halos / invalid rows
  for (int r = 0; r < 4; ++r) {
    int gh = h0 - 1 + r;
    if (gh >= 0 && gh < HW) {
      const uint4* src = (const uint4*)(xT + ((size_t)(b * HW + gh) * HW) * CIN);
      for (int idx = tid; idx < 448; idx += 256) {
        int w = idx >> 3, co = (idx & 7) * 8;
        *(uint4*)&xl[(r * 58 + 1 + w) * XLS + co] = src[idx];
      }
      if (tid < 16) {
        int col = (tid >> 3) ? 57 : 0, co = (tid & 7) * 8;
        *(uint4*)&xl[(r * 58 + col) * XLS + co] = (uint4){0, 0, 0, 0};
      }
    } else {
      for (int idx = tid; idx < 464; idx += 256) {
        int w = idx >> 3, co = (idx & 7) * 8;
        *(uint4*)&xl[(r * 58 + w) * XLS + co] = (uint4){0, 0, 0, 0};
      }
    }
  }

  short8 Bf[2][2][4];   // [parity][ck][nt]
  #pragma unroll
  for (int ck = 0; ck < 2; ++ck)
    #pragma unroll
    for (int nt = 0; nt < 4; ++nt)
      Bf[0][ck][nt] = *(const short8*)(wb0 + (size_t)(nt * 16) * CIN + ck * 32);

  floatx4 acc[7][4];
  #pragma unroll
  for (int t = 0; t < 7; ++t)
    #pragma unroll
    for (int nt = 0; nt < 4; ++nt) acc[t][nt] = (floatx4){0.f, 0.f, 0.f, 0.f};

  __syncthreads();

  // ---- K-loop: 9 taps, zero barriers, weights prefetched one tap ahead
  #pragma unroll
  for (int tap = 0; tap < 9; ++tap) {
    const int p = tap & 1;
    if (tap < 8) {
      #pragma unroll
      for (int ck = 0; ck < 2; ++ck)
        #pragma unroll
        for (int nt = 0; nt < 4; ++nt)
          Bf[p ^ 1][ck][nt] =
              *(const short8*)(wb0 + ((size_t)(tap + 1) * OC + nt * 16) * CIN + ck * 32);
    }
    const int kh = tap / 3, kw = tap - kh * 3;
    #pragma unroll
    for (int ck = 0; ck < 2; ++ck) {
      #pragma unroll
      for (int t = 0; t < 7; ++t) {
        short8 af = *(const short8*)&xl[abase[t] + (kh * 58 + kw) * XLS + ck * 32];
        #pragma unroll
        for (int nt = 0; nt < 4; ++nt)
          acc[t][nt] = __builtin_amdgcn_mfma_f32_16x16x32_bf16(af, Bf[p][ck][nt], acc[t][nt], 0, 0, 0);
      }
    }
  }

  // ---- epilogue: identity store, lanes l15 contiguous
  ushort_t* y = yq + (size_t)s * PEL;
  #pragma unroll
  for (int t = 0; t < 7; ++t) {
    #pragma unroll
    for (int r = 0; r < 4; ++r) {
      int pix = t * 16 + quad * 4 + r;
      int row = pix / HW, ww = pix - row * HW;
      size_t pb = ((size_t)((b * HW + h0 + row) * HW + ww)) * OC;
      #pragma unroll
      for (int nt = 0; nt < 4; ++nt) {
        int oc = ob * 256 + wv * 64 + nt * 16 + l15;
        y[pb + oc] = f2bf(acc[t][nt][r]);
      }
    }
  }
}

// ---------------------------------------------------------------------------
// Kernel 2: MFMA channel-attention + 1x1 conv + ReLU (r5 batched structure:
// 50us measured; r6-r9's per-nt serial P round trip measured 70us — the 16
// full lgkmcnt drains per wave cost 20us.  Keep BATCHED).
// Block = 16 pixels, 4 waves, wave = 4 pixels, prefetch one pixel ahead.
// launch_bounds(256,2): (256,6) caused 245MB spill traffic in r6.  LDS 53.5KB.
// ---------------------------------------------------------------------------
#define PST  72    // P LDS row stride (bf16 el): 144B rows, 16B-aligned
#define A2ST 520   // a2 stride: 16B-aligned, 2-way banks

__global__ __launch_bounds__(256, 2)
void attn_kernel(const ushort_t* __restrict__ q, const ushort_t* __restrict__ k,
                 const ushort_t* __restrict__ v, const ushort_t* __restrict__ WuP,
                 float* __restrict__ out) {
  __shared__ __align__(16) ushort_t Pl[4][64 * PST];   // per-wave P[qc][kc] bf16
  __shared__ __align__(16) ushort_t a2[16 * A2ST];     // attended [pix][c*8+n]

  const int tid  = threadIdx.x;
  const int lane = tid & 63;
  const int wv   = tid >> 6;
  const int l15  = lane & 15;
  const int quad = lane >> 4;
  const int p0   = blockIdx.x * 16;
  const int b    = blockIdx.y;
  const size_t ibase = ((size_t)b * NPIX + p0) * 512;

  ushort_t* Pw = &Pl[wv][0];
  const float scale = 0.044194173824159216f;  // 1/sqrt(512)

  auto loadpix = [&](int plocal, short8 qf[4], short8 kf[4], short8 vf[2]) {
    const ushort_t* qp = q + ibase + (size_t)plocal * 512;
    const ushort_t* kp = k + ibase + (size_t)plocal * 512;
    const ushort_t* vp = v + ibase + (size_t)plocal * 512;
    #pragma unroll
    for (int nt = 0; nt < 4; ++nt)
      qf[nt] = *(const short8*)(qp + (nt * 16 + l15) * 8);
    #pragma unroll
    for (int mt = 0; mt < 4; ++mt) {
      kf[mt] = (short8){0, 0, 0, 0, 0, 0, 0, 0};
      if (quad == 0) kf[mt] = *(const short8*)(kp + (mt * 16 + l15) * 8);
    }
    #pragma unroll
    for (int ck = 0; ck < 2; ++ck)
      vf[ck] = *(const short8*)(vp + (l15 & 7) * 64 + ck * 32 + quad * 8);
  };

  short8 qf[4], kf[4], vf[2];
  loadpix(wv * 4, qf, kf, vf);

  #pragma unroll
  for (int i = 0; i < 4; ++i) {
    const int plocal = wv * 4 + i;
    short8 qn[4], kn[4], vn[2];
    if (i < 3) loadpix(plocal + 1, qn, kn, vn);

    // ---- S^T[kc][qc] = k . q^T  (contraction n=8, padded in K=32 via A=0)
    floatx4 S[4][4];
    #pragma unroll
    for (int mt = 0; mt < 4; ++mt)
      #pragma unroll
      for (int nt = 0; nt < 4; ++nt) S[mt][nt] = (floatx4){0.f, 0.f, 0.f, 0.f};
    #pragma unroll
    for (int mt = 0; mt < 4; ++mt)
      #pragma unroll
      for (int nt = 0; nt < 4; ++nt)
        S[mt][nt] = __builtin_amdgcn_mfma_f32_16x16x32_bf16(kf[mt], qf[nt], S[mt][nt], 0, 0, 0);

    // ---- softmax ALL nt-tiles, write ALL P rows (batched -> one drain)
    #pragma unroll
    for (int nt = 0; nt < 4; ++nt) {
      float m = S[0][nt][0];
      #pragma unroll
      for (int mt = 0; mt < 4; ++mt)
        #pragma unroll
        for (int r = 0; r < 4; ++r) m = fmaxf(m, S[mt][nt][r]);
      m = fmaxf(m, __shfl_xor(m, 16));
      m = fmaxf(m, __shfl_xor(m, 32));
      float sum = 0.f;
      #pragma unroll
      for (int mt = 0; mt < 4; ++mt)
        #pragma unroll
        for (int r = 0; r < 4; ++r) {
          float e = __expf((S[mt][nt][r] - m) * scale);
          S[mt][nt][r] = e;
          sum += e;
        }
      sum += __shfl_xor(sum, 16);
      sum += __shfl_xor(sum, 32);
      float inv = __builtin_amdgcn_rcpf(sum);
      #pragma unroll
      for (int mt = 0; mt < 4; ++mt) {
        ushort4 w4;
        w4.x = f2bf(S[mt][nt][0] * inv);
        w4.y = f2bf(S[mt][nt][1] * inv);
        w4.z = f2bf(S[mt][nt][2] * inv);
        w4.w = f2bf(S[mt][nt][3] * inv);
        *(ushort4*)&Pw[(nt * 16 + l15) * PST + mt * 16 + quad * 4] = w4;
      }
    }

    // ---- attended^T[n][qc] = v^T . P^T   (M=n pad 16, N=qc 64, K=kc 64)
    floatx4 T[4];
    #pragma unroll
    for (int nt = 0; nt < 4; ++nt) T[nt] = (floatx4){0.f, 0.f, 0.f, 0.f};
    #pragma unroll
    for (int ck = 0; ck < 2; ++ck) {
      #pragma unroll
      for (int nt = 0; nt < 4; ++nt) {
        short8 pf = *(const short8*)&Pw[(nt * 16 + l15) * PST + ck * 32 + quad * 8];
        T[nt] = __builtin_amdgcn_mfma_f32_16x16x32_bf16(vf[ck], pf, T[nt], 0, 0, 0);
      }
    }
    if (quad < 2) {
      #pragma unroll
      for (int nt = 0; nt < 4; ++nt) {
        ushort4 w4;
        w4.x = f2bf(T[nt][0]);
        w4.y = f2bf(T[nt][1]);
        w4.z = f2bf(T[nt][2]);
        w4.w = f2bf(T[nt][3]);
        *(ushort4*)&a2[plocal * A2ST + (nt * 16 + l15) * 8 + quad * 4] = w4;
      }
    }

    if (i < 3) {
      #pragma unroll
      for (int z = 0; z < 4; ++z) { qf[z] = qn[z]; kf[z] = kn[z]; }
      vf[0] = vn[0];
      vf[1] = vn[1];
    }
  }
  __syncthreads();

  // ---- out GEMM: M=co(wave's 16), N=16 pixels, K=512
  floatx4 O = (floatx4){0.f, 0.f, 0.f, 0.f};
  #pragma unroll
  for (int ck = 0; ck < 16; ++ck) {
    short8 aw = *(const short8*)(WuP + (size_t)(wv * 16 + l15) * 512 + ck * 32 + quad * 8);
    short8 bw = *(const short8*)&a2[l15 * A2ST + ck * 32 + quad * 8];
    O = __builtin_amdgcn_mfma_f32_16x16x32_bf16(aw, bw, O, 0, 0, 0);
  }
  #pragma unroll
  for (int r = 0; r < 4; ++r) {
    int co = wv * 16 + quad * 4 + r;
    out[((size_t)b * 64 + co) * NPIX + p0 + l15] = fmaxf(O[r], 0.f);
  }
}

// ---------------------------------------------------------------------------
extern "C" void kernel_launch(void* const* d_in, const int* in_sizes, int n_in,
                              void* d_out, int out_size, void* d_ws, size_t ws_size,
                              hipStream_t stream) {
  const float* x  = (const float*)d_in[0];
  const float* Wq = (const float*)d_in[1];
  const float* Wk = (const float*)d_in[2];
  const float* Wv = (const float*)d_in[3];
  const float* Wu = (const float*)d_in[4];
  float* out = (float*)d_out;

  const size_t xT_elems = (size_t)8 * NPIX * CIN;
  const size_t w_elems  = (size_t)9 * OC * CIN;
  const size_t wu_elems = (size_t)64 * 512;
  ushort_t* xT  = (ushort_t*)d_ws;
  ushort_t* Wb  = xT + xT_elems;          // 27 taps: q(9) k(9) v(9)
  ushort_t* WuP = Wb + 3 * w_elems;
  ushort_t* q   = WuP + wu_elems;
  ushort_t* k   = q + PEL;
  ushort_t* v   = k + PEL;

  cast_x_kernel<<<dim3(HW, 8), 256, 0, stream>>>(x, xT);
  cast_w_kernel<<<dim3(OC, 3), 64, 0, stream>>>(Wq, Wk, Wv, Wb);
  cast_wu_kernel<<<64, 512, 0, stream>>>(Wu, WuP);

  dim3 cgrid(28, 2, 24);  // (row pairs, 256-oc halves, b + 8*s)
  conv3x3_qkv<<<cgrid, 256, 0, stream>>>(xT, Wb, q);

  attn_kernel<<<dim3(NPIX / 16, 8), 256, 0, stream>>>(q, k, v, WuP, out);
}

// Round 12
// 175.265 us; speedup vs baseline: 1.0613x; 1.0613x over previous
//
#include <hip/hip_runtime.h>
#include <hip/hip_bf16.h>

#define HW   56
#define CIN  64
#define OC   512
#define NPIX (HW * HW)   // 3136
#define PEL  ((size_t)8 * NPIX * OC)   // elements per q/k/v tensor

typedef unsigned short ushort_t;
typedef __attribute__((ext_vector_type(8))) short short8;
typedef __attribute__((ext_vector_type(4))) float floatx4;
typedef __attribute__((ext_vector_type(16))) float floatx16;

static __device__ __forceinline__ ushort_t f2bf(float f) {
  __hip_bfloat16 h = __float2bfloat16(f);
  return *(ushort_t*)&h;
}

// ---------------------------------------------------------------------------
// Prepass (merged): one kernel, 960 blocks x 256 thr, branch on blockIdx.x.
//  [0,448):  x NCHW fp32 -> xT [b][h][w][c] bf16
//  [448,832): W [oc][cin][3][3] -> Wb [tap][j][cin] bf16 (q,k rows permuted
//             j=c*8+n <- oc=n*64+c so conv stores are identity; v identity)
//  [832,960): Wu fp32 -> bf16 identity
// ---------------------------------------------------------------------------
__global__ __launch_bounds__(256)
void prep_kernel(const float* __restrict__ x, const float* __restrict__ W0,
                 const float* __restrict__ W1, const float* __restrict__ W2,
                 const float* __restrict__ Wu, ushort_t* __restrict__ xT,
                 ushort_t* __restrict__ Wb, ushort_t* __restrict__ WuP) {
  __shared__ ushort_t lx[CIN * HW];
  const int bid = blockIdx.x;
  const int tid = threadIdx.x;

  if (bid < 448) {
    const int h = bid % HW, b = bid / HW;
    for (int idx = tid; idx < CIN * HW; idx += 256) {
      int c = idx / HW, w = idx - c * HW;
      lx[idx] = f2bf(x[((size_t)(b * CIN + c) * HW + h) * HW + w]);
    }
    __syncthreads();
    ushort_t* dst = xT + ((size_t)(b * HW + h)) * HW * CIN;
    for (int i = tid; i < (CIN * HW) / 4; i += 256) {
      int e0 = i * 4;
      int w = e0 >> 6, c0 = e0 & 63;
      ushort4 o;
      o.x = lx[(c0 + 0) * HW + w];
      o.y = lx[(c0 + 1) * HW + w];
      o.z = lx[(c0 + 2) * HW + w];
      o.w = lx[(c0 + 3) * HW + w];
      ((ushort4*)dst)[i] = o;
    }
  } else if (bid < 832) {
    const int u = bid - 448;           // [0,384)
    const int sel = u / 128;
    const int j = (u % 128) * 4 + (tid >> 6);
    const int cin = tid & 63;
    const float* W = sel == 0 ? W0 : (sel == 1 ? W1 : W2);
    ushort_t* Ds = Wb + (size_t)sel * 9 * OC * CIN;
    const int src = (sel < 2) ? ((j & 7) * 64 + (j >> 3)) : j;
    #pragma unroll
    for (int tap = 0; tap < 9; ++tap)
      Ds[((size_t)tap * OC + j) * CIN + cin] = f2bf(W[(size_t)src * 576 + cin * 9 + tap]);
  } else {
    const int el = (bid - 832) * 256 + tid;   // [0, 32768)
    WuP[el] = f2bf(Wu[el]);
  }
}

// ---------------------------------------------------------------------------
// Kernel 1: q/k/v 3x3 conv via MFMA **32x32x16** bf16 implicit GEMM.
// 32K FLOP per 1KB ds_read (2x the 16x16x32 structure); half the MFMA insts.
// Block: 4 rows (224 px = 7 m-tiles of 32) x 128 oc; wave = 32-oc slice.
// A: m=lane&31, k-els 8 contiguous at khi*8 (A/B k-mapping symmetric, so any
// k-permutation cancels in the contraction).  C/D: col(oc)=lane&31,
// row(px)=(reg&3)+8*(reg>>2)+4*(lane>>5)  [HW-verified m74/m101].
// r11 BUG FIXED: abase must NOT add the +1 halo offset (staging already
// places pixel w at column 1+w; read col for output ww, tap kw is ww+kw).
// ---------------------------------------------------------------------------
#define XLS 72             // padded cin stride in x LDS tile (bf16 units)
#define XROW (58 * XLS)

__global__ __launch_bounds__(256, 2)
void conv3x3_qkv(const ushort_t* __restrict__ xT, const ushort_t* __restrict__ Wb,
                 ushort_t* __restrict__ yq) {
  __shared__ __align__(16) ushort_t xl[6 * XROW];   // 50112 B

  const int tid  = threadIdx.x;
  const int lane = tid & 63;
  const int wv   = tid >> 6;
  const int g    = blockIdx.x;        // [0,14): 4-row group
  const int ob   = blockIdx.y;        // [0,4): 128-oc slice
  const int b    = blockIdx.z & 7;
  const int s    = blockIdx.z >> 3;   // tensor: 0=q 1=k 2=v
  const int h0   = g * 4;
  const int l31  = lane & 31;
  const int khi  = lane >> 5;         // 0/1: K-half

  // A base per m-tile: pixel p = t*32 + l31 within the 4-row strip
  int abase[7];
  #pragma unroll
  for (int t = 0; t < 7; ++t) {
    int p = t * 32 + l31;
    int row = p / HW, ww = p - row * HW;
    abase[t] = (row * 58 + ww) * XLS + khi * 8;   // no +1 (r11 bug)
  }

  // B base: tensor s, oc = ob*128 + wv*32 + l31, k els khi*8..+7
  const ushort_t* wb0 = Wb + (size_t)s * 9 * OC * CIN +
                        ((size_t)(ob * 128 + wv * 32 + l31)) * CIN + khi * 8;

  // ---- stage x rows h0-1 .. h0+4; zero halos / invalid rows
  for (int r = 0; r < 6; ++r) {
    int gh = h0 - 1 + r;
    if (gh >= 0 && gh < HW) {
      const uint4* src = (const uint4*)(xT + ((size_t)(b * HW + gh) * HW) * CIN);
      for (int idx = tid; idx < 448; idx += 256) {
        int w = idx >> 3, co = (idx & 7) * 8;
        *(uint4*)&xl[(r * 58 + 1 + w) * XLS + co] = src[idx];
      }
      if (tid < 16) {
        int col = (tid >> 3) ? 57 : 0, co = (tid & 7) * 8;
        *(uint4*)&xl[(r * 58 + col) * XLS + co] = (uint4){0, 0, 0, 0};
      }
    } else {
      for (int idx = tid; idx < 464; idx += 256) {
        int w = idx >> 3, co = (idx & 7) * 8;
        *(uint4*)&xl[(r * 58 + w) * XLS + co] = (uint4){0, 0, 0, 0};
      }
    }
  }

  short8 Bf[2][4];   // [parity][ck], K=16 chunks: cin = ck*16 + khi*8..+7
  #pragma unroll
  for (int ck = 0; ck < 4; ++ck)
    Bf[0][ck] = *(const short8*)(wb0 + ck * 16);

  floatx16 acc[7];
  #pragma unroll
  for (int t = 0; t < 7; ++t) acc[t] = (floatx16)(0.0f);

  __syncthreads();

  // ---- K-loop: 9 taps, zero barriers, weights prefetched one tap ahead
  #pragma unroll
  for (int tap = 0; tap < 9; ++tap) {
    const int p = tap & 1;
    if (tap < 8) {
      #pragma unroll
      for (int ck = 0; ck < 4; ++ck)
        Bf[p ^ 1][ck] = *(const short8*)(wb0 + (size_t)(tap + 1) * OC * CIN + ck * 16);
    }
    const int kh = tap / 3, kw = tap - kh * 3;
    #pragma unroll
    for (int ck = 0; ck < 4; ++ck) {
      #pragma unroll
      for (int t = 0; t < 7; ++t) {
        short8 af = *(const short8*)&xl[abase[t] + (kh * 58 + kw) * XLS + ck * 16];
        acc[t] = __builtin_amdgcn_mfma_f32_32x32x16_bf16(af, Bf[p][ck], acc[t], 0, 0, 0);
      }
    }
  }

  // ---- epilogue: D col=oc=l31 (contiguous stores), row=px
  ushort_t* y = yq + (size_t)s * PEL;
  const int oc = ob * 128 + wv * 32 + l31;
  #pragma unroll
  for (int t = 0; t < 7; ++t) {
    #pragma unroll
    for (int i = 0; i < 16; ++i) {
      int p = t * 32 + (i & 3) + 8 * (i >> 2) + 4 * khi;
      int row = p / HW, ww = p - row * HW;
      size_t pb = ((size_t)((b * HW + h0 + row) * HW + ww)) * OC;
      y[pb + oc] = f2bf(acc[t][i]);
    }
  }
}

// ---------------------------------------------------------------------------
// Kernel 2: MFMA channel-attention + 1x1 conv + ReLU (r5 structure, proven
// 50us: batched softmax + big per-wave Pl, prefetch one pixel ahead).
// launch_bounds(256,2): (256,6) caused 245MB spill traffic in r6.
// ---------------------------------------------------------------------------
#define PST  72    // P LDS row stride (bf16 el): 144B rows, 16B-aligned
#define A2ST 520   // a2 stride: 16B-aligned, 2-way banks

__global__ __launch_bounds__(256, 2)
void attn_kernel(const ushort_t* __restrict__ q, const ushort_t* __restrict__ k,
                 const ushort_t* __restrict__ v, const ushort_t* __restrict__ WuP,
                 float* __restrict__ out) {
  __shared__ __align__(16) ushort_t Pl[4][64 * PST];   // per-wave P[qc][kc] bf16
  __shared__ __align__(16) ushort_t a2[16 * A2ST];     // attended [pix][c*8+n]

  const int tid  = threadIdx.x;
  const int lane = tid & 63;
  const int wv   = tid >> 6;
  const int l15  = lane & 15;
  const int quad = lane >> 4;
  const int p0   = blockIdx.x * 16;
  const int b    = blockIdx.y;
  const size_t ibase = ((size_t)b * NPIX + p0) * 512;

  ushort_t* Pw = &Pl[wv][0];
  const float scale = 0.044194173824159216f;  // 1/sqrt(512)

  auto loadpix = [&](int plocal, short8 qf[4], short8 kf[4], short8 vf[2]) {
    const ushort_t* qp = q + ibase + (size_t)plocal * 512;
    const ushort_t* kp = k + ibase + (size_t)plocal * 512;
    const ushort_t* vp = v + ibase + (size_t)plocal * 512;
    #pragma unroll
    for (int nt = 0; nt < 4; ++nt)
      qf[nt] = *(const short8*)(qp + (nt * 16 + l15) * 8);
    #pragma unroll
    for (int mt = 0; mt < 4; ++mt) {
      kf[mt] = (short8){0, 0, 0, 0, 0, 0, 0, 0};
      if (quad == 0) kf[mt] = *(const short8*)(kp + (mt * 16 + l15) * 8);
    }
    #pragma unroll
    for (int ck = 0; ck < 2; ++ck)
      vf[ck] = *(const short8*)(vp + (l15 & 7) * 64 + ck * 32 + quad * 8);
  };

  short8 qf[4], kf[4], vf[2];
  loadpix(wv * 4, qf, kf, vf);

  #pragma unroll
  for (int i = 0; i < 4; ++i) {
    const int plocal = wv * 4 + i;
    short8 qn[4], kn[4], vn[2];
    if (i < 3) loadpix(plocal + 1, qn, kn, vn);

    // ---- S^T[kc][qc] = k . q^T  (contraction n=8, padded in K=32 via A=0)
    floatx4 S[4][4];
    #pragma unroll
    for (int mt = 0; mt < 4; ++mt)
      #pragma unroll
      for (int nt = 0; nt < 4; ++nt) S[mt][nt] = (floatx4){0.f, 0.f, 0.f, 0.f};
    #pragma unroll
    for (int mt = 0; mt < 4; ++mt)
      #pragma unroll
      for (int nt = 0; nt < 4; ++nt)
        S[mt][nt] = __builtin_amdgcn_mfma_f32_16x16x32_bf16(kf[mt], qf[nt], S[mt][nt], 0, 0, 0);

    // ---- softmax ALL nt-tiles, write ALL P rows (batched -> one drain)
    #pragma unroll
    for (int nt = 0; nt < 4; ++nt) {
      float m = S[0][nt][0];
      #pragma unroll
      for (int mt = 0; mt < 4; ++mt)
        #pragma unroll
        for (int r = 0; r < 4; ++r) m = fmaxf(m, S[mt][nt][r]);
      m = fmaxf(m, __shfl_xor(m, 16));
      m = fmaxf(m, __shfl_xor(m, 32));
      float sum = 0.f;
      #pragma unroll
      for (int mt = 0; mt < 4; ++mt)
        #pragma unroll
        for (int r = 0; r < 4; ++r) {
          float e = __expf((S[mt][nt][r] - m) * scale);
          S[mt][nt][r] = e;
          sum += e;
        }
      sum += __shfl_xor(sum, 16);
      sum += __shfl_xor(sum, 32);
      float inv = __builtin_amdgcn_rcpf(sum);
      #pragma unroll
      for (int mt = 0; mt < 4; ++mt) {
        ushort4 w4;
        w4.x = f2bf(S[mt][nt][0] * inv);
        w4.y = f2bf(S[mt][nt][1] * inv);
        w4.z = f2bf(S[mt][nt][2] * inv);
        w4.w = f2bf(S[mt][nt][3] * inv);
        *(ushort4*)&Pw[(nt * 16 + l15) * PST + mt * 16 + quad * 4] = w4;
      }
    }

    // ---- attended^T[n][qc] = v^T . P^T   (M=n pad 16, N=qc 64, K=kc 64)
    floatx4 T[4];
    #pragma unroll
    for (int nt = 0; nt < 4; ++nt) T[nt] = (floatx4){0.f, 0.f, 0.f, 0.f};
    #pragma unroll
    for (int ck = 0; ck < 2; ++ck) {
      #pragma unroll
      for (int nt = 0; nt < 4; ++nt) {
        short8 pf = *(const short8*)&Pw[(nt * 16 + l15) * PST + ck * 32 + quad * 8];
        T[nt] = __builtin_amdgcn_mfma_f32_16x16x32_bf16(vf[ck], pf, T[nt], 0, 0, 0);
      }
    }
    if (quad < 2) {
      #pragma unroll
      for (int nt = 0; nt < 4; ++nt) {
        ushort4 w4;
        w4.x = f2bf(T[nt][0]);
        w4.y = f2bf(T[nt][1]);
        w4.z = f2bf(T[nt][2]);
        w4.w = f2bf(T[nt][3]);
        *(ushort4*)&a2[plocal * A2ST + (nt * 16 + l15) * 8 + quad * 4] = w4;
      }
    }

    if (i < 3) {
      #pragma unroll
      for (int z = 0; z < 4; ++z) { qf[z] = qn[z]; kf[z] = kn[z]; }
      vf[0] = vn[0];
      vf[1] = vn[1];
    }
  }
  __syncthreads();

  // ---- out GEMM: M=co(wave's 16), N=16 pixels, K=512
  floatx4 O = (floatx4){0.f, 0.f, 0.f, 0.f};
  #pragma unroll
  for (int ck = 0; ck < 16; ++ck) {
    short8 aw = *(const short8*)(WuP + (size_t)(wv * 16 + l15) * 512 + ck * 32 + quad * 8);
    short8 bw = *(const short8*)&a2[l15 * A2ST + ck * 32 + quad * 8];
    O = __builtin_amdgcn_mfma_f32_16x16x32_bf16(aw, bw, O, 0, 0, 0);
  }
  #pragma unroll
  for (int r = 0; r < 4; ++r) {
    int co = wv * 16 + quad * 4 + r;
    out[((size_t)b * 64 + co) * NPIX + p0 + l15] = fmaxf(O[r], 0.f);
  }
}

// ---------------------------------------------------------------------------
extern "C" void kernel_launch(void* const* d_in, const int* in_sizes, int n_in,
                              void* d_out, int out_size, void* d_ws, size_t ws_size,
                              hipStream_t stream) {
  const float* x  = (const float*)d_in[0];
  const float* Wq = (const float*)d_in[1];
  const float* Wk = (const float*)d_in[2];
  const float* Wv = (const float*)d_in[3];
  const float* Wu = (const float*)d_in[4];
  float* out = (float*)d_out;

  const size_t xT_elems = (size_t)8 * NPIX * CIN;
  const size_t w_elems  = (size_t)9 * OC * CIN;
  const size_t wu_elems = (size_t)64 * 512;
  ushort_t* xT  = (ushort_t*)d_ws;
  ushort_t* Wb  = xT + xT_elems;          // 27 taps: q(9) k(9) v(9)
  ushort_t* WuP = Wb + 3 * w_elems;
  ushort_t* q   = WuP + wu_elems;
  ushort_t* k   = q + PEL;
  ushort_t* v   = k + PEL;

  prep_kernel<<<960, 256, 0, stream>>>(x, Wq, Wk, Wv, Wu, xT, Wb, WuP);

  dim3 cgrid(14, 4, 24);  // (4-row groups, 128-oc slices, b + 8*s)
  conv3x3_qkv<<<cgrid, 256, 0, stream>>>(xT, Wb, q);

  attn_kernel<<<dim3(NPIX / 16, 8), 256, 0, stream>>>(q, k, v, WuP, out);
}

// Round 13
// 168.172 us; speedup vs baseline: 1.1061x; 1.0422x over previous
//
#include <hip/hip_runtime.h>
#include <hip/hip_bf16.h>

#define HW   56
#define CIN  64
#define OC   512
#define NPIX (HW * HW)   // 3136
#define PEL  ((size_t)8 * NPIX * OC)   // elements per q/k/v tensor

typedef unsigned short ushort_t;
typedef __attribute__((ext_vector_type(8))) short short8;
typedef __attribute__((ext_vector_type(4))) float floatx4;
typedef __attribute__((ext_vector_type(16))) float floatx16;

static __device__ __forceinline__ ushort_t f2bf(float f) {
  __hip_bfloat16 h = __float2bfloat16(f);
  return *(ushort_t*)&h;
}

// ---------------------------------------------------------------------------
// Prepass (merged): one kernel, 960 blocks x 256 thr, branch on blockIdx.x.
//  [0,448):  x NCHW fp32 -> xT [b][h][w][c] bf16
//  [448,832): W [oc][cin][3][3] -> Wb [tap][j][cin] bf16 (q,k rows permuted
//             j=c*8+n <- oc=n*64+c so conv stores are identity; v identity)
//  [832,960): Wu fp32 -> bf16 identity
// ---------------------------------------------------------------------------
__global__ __launch_bounds__(256)
void prep_kernel(const float* __restrict__ x, const float* __restrict__ W0,
                 const float* __restrict__ W1, const float* __restrict__ W2,
                 const float* __restrict__ Wu, ushort_t* __restrict__ xT,
                 ushort_t* __restrict__ Wb, ushort_t* __restrict__ WuP) {
  __shared__ ushort_t lx[CIN * HW];
  const int bid = blockIdx.x;
  const int tid = threadIdx.x;

  if (bid < 448) {
    const int h = bid % HW, b = bid / HW;
    for (int idx = tid; idx < CIN * HW; idx += 256) {
      int c = idx / HW, w = idx - c * HW;
      lx[idx] = f2bf(x[((size_t)(b * CIN + c) * HW + h) * HW + w]);
    }
    __syncthreads();
    ushort_t* dst = xT + ((size_t)(b * HW + h)) * HW * CIN;
    for (int i = tid; i < (CIN * HW) / 4; i += 256) {
      int e0 = i * 4;
      int w = e0 >> 6, c0 = e0 & 63;
      ushort4 o;
      o.x = lx[(c0 + 0) * HW + w];
      o.y = lx[(c0 + 1) * HW + w];
      o.z = lx[(c0 + 2) * HW + w];
      o.w = lx[(c0 + 3) * HW + w];
      ((ushort4*)dst)[i] = o;
    }
  } else if (bid < 832) {
    const int u = bid - 448;           // [0,384)
    const int sel = u / 128;
    const int j = (u % 128) * 4 + (tid >> 6);
    const int cin = tid & 63;
    const float* W = sel == 0 ? W0 : (sel == 1 ? W1 : W2);
    ushort_t* Ds = Wb + (size_t)sel * 9 * OC * CIN;
    const int src = (sel < 2) ? ((j & 7) * 64 + (j >> 3)) : j;
    #pragma unroll
    for (int tap = 0; tap < 9; ++tap)
      Ds[((size_t)tap * OC + j) * CIN + cin] = f2bf(W[(size_t)src * 576 + cin * 9 + tap]);
  } else {
    const int el = (bid - 832) * 256 + tid;   // [0, 32768)
    WuP[el] = f2bf(Wu[el]);
  }
}

// ---------------------------------------------------------------------------
// Kernel 1: q/k/v 3x3 conv via MFMA 32x32x16 bf16 implicit GEMM.
// Block: 4 rows (224 px = 7 m-tiles of 32) x 128 oc; wave = 32-oc slice.
// r12: A-reads stride 36 dwords == 4 mod 32 -> lanes {i,i+8,i+16,i+24}
// alias = 4-way bank conflict (SQ_LDS_BANK_CONFLICT 2.3e6, ~14% LDS-pipe
// overhead).  Fix: SWIZZLE the 16B chunk index per column:
//   phys_chunk = (c8 + 2*((col>>3)&3)) & 7
// -> the 4 aliasing lanes get +{0,8,16,24} mod 32 -> distinct banks.
// Staging writes and A-reads both apply it.
// ---------------------------------------------------------------------------
#define XLS 72             // padded cin stride in x LDS tile (bf16 units)
#define XROW (58 * XLS)

__global__ __launch_bounds__(256, 2)
void conv3x3_qkv(const ushort_t* __restrict__ xT, const ushort_t* __restrict__ Wb,
                 ushort_t* __restrict__ yq) {
  __shared__ __align__(16) ushort_t xl[6 * XROW];   // 50112 B

  const int tid  = threadIdx.x;
  const int lane = tid & 63;
  const int wv   = tid >> 6;
  const int g    = blockIdx.x;        // [0,14): 4-row group
  const int ob   = blockIdx.y;        // [0,4): 128-oc slice
  const int b    = blockIdx.z & 7;
  const int s    = blockIdx.z >> 3;   // tensor: 0=q 1=k 2=v
  const int h0   = g * 4;
  const int l31  = lane & 31;
  const int khi  = lane >> 5;         // 0/1: K-half

  // A per m-tile: pixel p = t*32 + l31 within the 4-row strip
  int rowcol[7], wwv[7];
  #pragma unroll
  for (int t = 0; t < 7; ++t) {
    int p = t * 32 + l31;
    int row = p / HW, ww = p - row * HW;
    rowcol[t] = (row * 58 + ww) * XLS;
    wwv[t] = ww;
  }

  // B base: tensor s, oc = ob*128 + wv*32 + l31, k els khi*8..+7
  const ushort_t* wb0 = Wb + (size_t)s * 9 * OC * CIN +
                        ((size_t)(ob * 128 + wv * 32 + l31)) * CIN + khi * 8;

  // ---- stage x rows h0-1 .. h0+4 with chunk swizzle; zero halos / bad rows
  for (int r = 0; r < 6; ++r) {
    int gh = h0 - 1 + r;
    if (gh >= 0 && gh < HW) {
      const uint4* src = (const uint4*)(xT + ((size_t)(b * HW + gh) * HW) * CIN);
      for (int idx = tid; idx < 448; idx += 256) {
        int w = idx >> 3, c8 = idx & 7;
        int col = 1 + w;
        int p8 = (c8 + 2 * ((col >> 3) & 3)) & 7;
        *(uint4*)&xl[(r * 58 + col) * XLS + p8 * 8] = src[idx];
      }
      if (tid < 16) {
        int col = (tid >> 3) ? 57 : 0, c8 = tid & 7;
        int p8 = (c8 + 2 * ((col >> 3) & 3)) & 7;
        *(uint4*)&xl[(r * 58 + col) * XLS + p8 * 8] = (uint4){0, 0, 0, 0};
      }
    } else {
      for (int idx = tid; idx < 464; idx += 256) {
        int col = idx >> 3, c8 = idx & 7;
        int p8 = (c8 + 2 * ((col >> 3) & 3)) & 7;
        *(uint4*)&xl[(r * 58 + col) * XLS + p8 * 8] = (uint4){0, 0, 0, 0};
      }
    }
  }

  short8 Bf[2][4];   // [parity][ck], K=16 chunks: cin = ck*16 + khi*8..+7
  #pragma unroll
  for (int ck = 0; ck < 4; ++ck)
    Bf[0][ck] = *(const short8*)(wb0 + ck * 16);

  floatx16 acc[7];
  #pragma unroll
  for (int t = 0; t < 7; ++t) acc[t] = (floatx16)(0.0f);

  __syncthreads();

  // ---- K-loop: 9 taps, zero barriers, weights prefetched one tap ahead
  #pragma unroll
  for (int tap = 0; tap < 9; ++tap) {
    const int p = tap & 1;
    if (tap < 8) {
      #pragma unroll
      for (int ck = 0; ck < 4; ++ck)
        Bf[p ^ 1][ck] = *(const short8*)(wb0 + (size_t)(tap + 1) * OC * CIN + ck * 16);
    }
    const int kh = tap / 3, kw = tap - kh * 3;
    int baddr[7], b8[7];
    #pragma unroll
    for (int t = 0; t < 7; ++t) {
      int j = wwv[t] + kw;                  // LDS column read for this tap
      baddr[t] = rowcol[t] + (kh * 58 + kw) * XLS;
      b8[t] = khi + 2 * ((j >> 3) & 3);
    }
    #pragma unroll
    for (int ck = 0; ck < 4; ++ck) {
      #pragma unroll
      for (int t = 0; t < 7; ++t) {
        int chunk = (b8[t] + 2 * ck) & 7;
        short8 af = *(const short8*)&xl[baddr[t] + chunk * 8];
        acc[t] = __builtin_amdgcn_mfma_f32_32x32x16_bf16(af, Bf[p][ck], acc[t], 0, 0, 0);
      }
    }
  }

  // ---- epilogue: D col=oc=l31 (contiguous stores), row=px [m74/m101]
  ushort_t* y = yq + (size_t)s * PEL;
  const int oc = ob * 128 + wv * 32 + l31;
  #pragma unroll
  for (int t = 0; t < 7; ++t) {
    #pragma unroll
    for (int i = 0; i < 16; ++i) {
      int p = t * 32 + (i & 3) + 8 * (i >> 2) + 4 * khi;
      int row = p / HW, ww = p - row * HW;
      size_t pb = ((size_t)((b * HW + h0 + row) * HW + ww)) * OC;
      y[pb + oc] = f2bf(acc[t][i]);
    }
  }
}

// ---------------------------------------------------------------------------
// Kernel 2: MFMA channel-attention + 1x1 conv + ReLU (r5 batched structure).
// launch_bounds(256,3): LDS 53504*3 = 160.5KB fits; live regs ~132 (68 VGPR
// + 64 AGPR for S) < 170 cap -> 3 blocks/CU = 12 waves (was 2/8).
// Spill tripwire: WRITE_SIZE must stay ~6.3MB (r6: cap 85 caused 245MB).
// ---------------------------------------------------------------------------
#define PST  72    // P LDS row stride (bf16 el): 144B rows, 16B-aligned
#define A2ST 520   // a2 stride: 16B-aligned, 2-way banks

__global__ __launch_bounds__(256, 3)
void attn_kernel(const ushort_t* __restrict__ q, const ushort_t* __restrict__ k,
                 const ushort_t* __restrict__ v, const ushort_t* __restrict__ WuP,
                 float* __restrict__ out) {
  __shared__ __align__(16) ushort_t Pl[4][64 * PST];   // per-wave P[qc][kc] bf16
  __shared__ __align__(16) ushort_t a2[16 * A2ST];     // attended [pix][c*8+n]

  const int tid  = threadIdx.x;
  const int lane = tid & 63;
  const int wv   = tid >> 6;
  const int l15  = lane & 15;
  const int quad = lane >> 4;
  const int p0   = blockIdx.x * 16;
  const int b    = blockIdx.y;
  const size_t ibase = ((size_t)b * NPIX + p0) * 512;

  ushort_t* Pw = &Pl[wv][0];
  const float scale = 0.044194173824159216f;  // 1/sqrt(512)

  auto loadpix = [&](int plocal, short8 qf[4], short8 kf[4], short8 vf[2]) {
    const ushort_t* qp = q + ibase + (size_t)plocal * 512;
    const ushort_t* kp = k + ibase + (size_t)plocal * 512;
    const ushort_t* vp = v + ibase + (size_t)plocal * 512;
    #pragma unroll
    for (int nt = 0; nt < 4; ++nt)
      qf[nt] = *(const short8*)(qp + (nt * 16 + l15) * 8);
    #pragma unroll
    for (int mt = 0; mt < 4; ++mt) {
      kf[mt] = (short8){0, 0, 0, 0, 0, 0, 0, 0};
      if (quad == 0) kf[mt] = *(const short8*)(kp + (mt * 16 + l15) * 8);
    }
    #pragma unroll
    for (int ck = 0; ck < 2; ++ck)
      vf[ck] = *(const short8*)(vp + (l15 & 7) * 64 + ck * 32 + quad * 8);
  };

  short8 qf[4], kf[4], vf[2];
  loadpix(wv * 4, qf, kf, vf);

  #pragma unroll
  for (int i = 0; i < 4; ++i) {
    const int plocal = wv * 4 + i;
    short8 qn[4], kn[4], vn[2];
    if (i < 3) loadpix(plocal + 1, qn, kn, vn);

    // ---- S^T[kc][qc] = k . q^T  (contraction n=8, padded in K=32 via A=0)
    floatx4 S[4][4];
    #pragma unroll
    for (int mt = 0; mt < 4; ++mt)
      #pragma unroll
      for (int nt = 0; nt < 4; ++nt) S[mt][nt] = (floatx4){0.f, 0.f, 0.f, 0.f};
    #pragma unroll
    for (int mt = 0; mt < 4; ++mt)
      #pragma unroll
      for (int nt = 0; nt < 4; ++nt)
        S[mt][nt] = __builtin_amdgcn_mfma_f32_16x16x32_bf16(kf[mt], qf[nt], S[mt][nt], 0, 0, 0);

    // ---- softmax ALL nt-tiles, write ALL P rows (batched -> one drain)
    #pragma unroll
    for (int nt = 0; nt < 4; ++nt) {
      float m = S[0][nt][0];
      #pragma unroll
      for (int mt = 0; mt < 4; ++mt)
        #pragma unroll
        for (int r = 0; r < 4; ++r) m = fmaxf(m, S[mt][nt][r]);
      m = fmaxf(m, __shfl_xor(m, 16));
      m = fmaxf(m, __shfl_xor(m, 32));
      float sum = 0.f;
      #pragma unroll
      for (int mt = 0; mt < 4; ++mt)
        #pragma unroll
        for (int r = 0; r < 4; ++r) {
          float e = __expf((S[mt][nt][r] - m) * scale);
          S[mt][nt][r] = e;
          sum += e;
        }
      sum += __shfl_xor(sum, 16);
      sum += __shfl_xor(sum, 32);
      float inv = __builtin_amdgcn_rcpf(sum);
      #pragma unroll
      for (int mt = 0; mt < 4; ++mt) {
        ushort4 w4;
        w4.x = f2bf(S[mt][nt][0] * inv);
        w4.y = f2bf(S[mt][nt][1] * inv);
        w4.z = f2bf(S[mt][nt][2] * inv);
        w4.w = f2bf(S[mt][nt][3] * inv);
        *(ushort4*)&Pw[(nt * 16 + l15) * PST + mt * 16 + quad * 4] = w4;
      }
    }

    // ---- attended^T[n][qc] = v^T . P^T   (M=n pad 16, N=qc 64, K=kc 64)
    floatx4 T[4];
    #pragma unroll
    for (int nt = 0; nt < 4; ++nt) T[nt] = (floatx4){0.f, 0.f, 0.f, 0.f};
    #pragma unroll
    for (int ck = 0; ck < 2; ++ck) {
      #pragma unroll
      for (int nt = 0; nt < 4; ++nt) {
        short8 pf = *(const short8*)&Pw[(nt * 16 + l15) * PST + ck * 32 + quad * 8];
        T[nt] = __builtin_amdgcn_mfma_f32_16x16x32_bf16(vf[ck], pf, T[nt], 0, 0, 0);
      }
    }
    if (quad < 2) {
      #pragma unroll
      for (int nt = 0; nt < 4; ++nt) {
        ushort4 w4;
        w4.x = f2bf(T[nt][0]);
        w4.y = f2bf(T[nt][1]);
        w4.z = f2bf(T[nt][2]);
        w4.w = f2bf(T[nt][3]);
        *(ushort4*)&a2[plocal * A2ST + (nt * 16 + l15) * 8 + quad * 4] = w4;
      }
    }

    if (i < 3) {
      #pragma unroll
      for (int z = 0; z < 4; ++z) { qf[z] = qn[z]; kf[z] = kn[z]; }
      vf[0] = vn[0];
      vf[1] = vn[1];
    }
  }
  __syncthreads();

  // ---- out GEMM: M=co(wave's 16), N=16 pixels, K=512
  floatx4 O = (floatx4){0.f, 0.f, 0.f, 0.f};
  #pragma unroll
  for (int ck = 0; ck < 16; ++ck) {
    short8 aw = *(const short8*)(WuP + (size_t)(wv * 16 + l15) * 512 + ck * 32 + quad * 8);
    short8 bw = *(const short8*)&a2[l15 * A2ST + ck * 32 + quad * 8];
    O = __builtin_amdgcn_mfma_f32_16x16x32_bf16(aw, bw, O, 0, 0, 0);
  }
  #pragma unroll
  for (int r = 0; r < 4; ++r) {
    int co = wv * 16 + quad * 4 + r;
    out[((size_t)b * 64 + co) * NPIX + p0 + l15] = fmaxf(O[r], 0.f);
  }
}

// ---------------------------------------------------------------------------
extern "C" void kernel_launch(void* const* d_in, const int* in_sizes, int n_in,
                              void* d_out, int out_size, void* d_ws, size_t ws_size,
                              hipStream_t stream) {
  const float* x  = (const float*)d_in[0];
  const float* Wq = (const float*)d_in[1];
  const float* Wk = (const float*)d_in[2];
  const float* Wv = (const float*)d_in[3];
  const float* Wu = (const float*)d_in[4];
  float* out = (float*)d_out;

  const size_t xT_elems = (size_t)8 * NPIX * CIN;
  const size_t w_elems  = (size_t)9 * OC * CIN;
  const size_t wu_elems = (size_t)64 * 512;
  ushort_t* xT  = (ushort_t*)d_ws;
  ushort_t* Wb  = xT + xT_elems;          // 27 taps: q(9) k(9) v(9)
  ushort_t* WuP = Wb + 3 * w_elems;
  ushort_t* q   = WuP + wu_elems;
  ushort_t* k   = q + PEL;
  ushort_t* v   = k + PEL;

  prep_kernel<<<960, 256, 0, stream>>>(x, Wq, Wk, Wv, Wu, xT, Wb, WuP);

  dim3 cgrid(14, 4, 24);  // (4-row groups, 128-oc slices, b + 8*s)
  conv3x3_qkv<<<cgrid, 256, 0, stream>>>(xT, Wb, q);

  attn_kernel<<<dim3(NPIX / 16, 8), 256, 0, stream>>>(q, k, v, WuP, out);
}